// Round 2
// baseline (754.370 us; speedup 1.0000x reference)
//
#include <hip/hip_runtime.h>

// Matcher: B=8, H=W=48, HW=2304.
// out[b,0..1,:]: global branch  max_p init_sim[b,p,j]*init_seg[b,c,p]
// out[b,2..3,:]: local branch   per-row top4/min on scaled prev_sim rows,
//                column max of (kept value | per-row fill).
#define B_   8
#define HW_  2304
#define NP   96              // p-chunks for global partials
#define RP   (HW_ / NP)      // 24 rows per chunk
#define NOUT (B_ * 4 * HW_)

// ws layout (uint units)
#define LACC_OFF 0                   // B*2*HW uint accumulators (local channels)
#define F_OFF    (B_ * 2 * HW_)      // 16 uints: per-(b,c) fill maxima
#define P_OFF    (F_OFF + 16)        // 8*2*96*2304 floats of global partials (16B aligned)

__global__ __launch_bounds__(256) void k_init(unsigned* __restrict__ ws) {
    int idx = blockIdx.x * 256 + threadIdx.x;
    if (idx < P_OFF) ws[idx] = 0u;   // lacc = 0.0f, F = 0.0f
}

// Global branch partials: grid (3 colTiles, NP, B), 192 threads.
// Each thread owns one float4 column group, streams RP rows, writes partial max.
__global__ __launch_bounds__(192) void k_global(const float* __restrict__ sim,
                                                const float* __restrict__ seg,
                                                float* __restrict__ P) {
    const int t  = threadIdx.x;
    const int np = blockIdx.y;
    const int b  = blockIdx.z;
    const int j4 = blockIdx.x * 192 + t;          // float4 column index 0..575
    const float4* simb = (const float4*)(sim + (size_t)b * HW_ * HW_) + j4;
    const float* sg = seg + (size_t)b * 2 * HW_;
    const int p0 = np * RP;
    const float NI = -__builtin_inff();
    float4 m0 = {NI, NI, NI, NI}, m1 = {NI, NI, NI, NI};
#pragma unroll
    for (int rr = 0; rr < RP; ++rr) {
        int p = p0 + rr;
        float4 v = simb[(size_t)p * (HW_ / 4)];
        float s0 = sg[p];
        float s1 = sg[HW_ + p];
        m0.x = fmaxf(m0.x, v.x * s0); m1.x = fmaxf(m1.x, v.x * s1);
        m0.y = fmaxf(m0.y, v.y * s0); m1.y = fmaxf(m1.y, v.y * s1);
        m0.z = fmaxf(m0.z, v.z * s0); m1.z = fmaxf(m1.z, v.z * s1);
        m0.w = fmaxf(m0.w, v.w * s0); m1.w = fmaxf(m1.w, v.w * s1);
    }
    float4* P4 = (float4*)P;
    P4[(((size_t)b * 2 + 0) * NP + np) * (HW_ / 4) + j4] = m0;
    P4[(((size_t)b * 2 + 1) * NP + np) * (HW_ / 4) + j4] = m1;
}

// Local branch: one wave per row. grid (18432/4), 256 threads (4 waves).
// No LDS, no __syncthreads: load row into regs, branchless top4+min,
// wave64 butterfly merge, register epilogue with sparse atomics.
__global__ __launch_bounds__(256, 4) void k_local(const float* __restrict__ sim,
                                                  const float* __restrict__ seg,
                                                  unsigned* __restrict__ lacc,
                                                  unsigned* __restrict__ F) {
    const int r    = blockIdx.x * 4 + (threadIdx.x >> 6);   // global row 0..18431
    const int lane = threadIdx.x & 63;
    const int b = r / HW_;
    const int i = r - b * HW_;
    const float4* row = (const float4*)(sim + (size_t)r * HW_);
    float x[36];
#pragma unroll
    for (int k = 0; k < 9; ++k) {
        float4 v = row[lane + k * 64];
        x[4 * k + 0] = v.x; x[4 * k + 1] = v.y;
        x[4 * k + 2] = v.z; x[4 * k + 3] = v.w;
    }
    const float NI = -__builtin_inff();
    float a0 = NI, a1 = NI, a2 = NI, a3 = NI, mn = __builtin_inff();
#pragma unroll
    for (int k = 0; k < 36; ++k) {
        float v = x[k];
        mn = fminf(mn, v);
        // branchless insert: discard min(a3,v), bubble w=max(a3,v) upward
        float w = fmaxf(a3, v);
        a3 = fminf(a2, w); w = fmaxf(a2, w);
        a2 = fminf(a1, w); w = fmaxf(a1, w);
        a1 = fminf(a0, w); a0 = fmaxf(a0, w);
    }
    // wave64 butterfly: merge sorted-desc 4-lists; lane0 ends with row result
#pragma unroll
    for (int off = 32; off >= 1; off >>= 1) {
        float b0 = __shfl_down(a0, off);
        float b1 = __shfl_down(a1, off);
        float b2 = __shfl_down(a2, off);
        float b3 = __shfl_down(a3, off);
        float bm = __shfl_down(mn, off);
        mn = fminf(mn, bm);
        float r0 = fmaxf(a0, b0);
        float r1 = fmaxf(fmaxf(a1, b1), fminf(a0, b0));
        float r2 = fmaxf(fmaxf(a2, b2), fmaxf(fminf(a1, b0), fminf(a0, b1)));
        float r3 = fmaxf(fmaxf(a3, b3),
                   fmaxf(fminf(a2, b0), fmaxf(fminf(a1, b1), fminf(a0, b2))));
        a0 = r0; a1 = r1; a2 = r2; a3 = r3;
    }
    const float t4r = __shfl(a3, 0);   // raw 4th-largest of row
    const float mnr = __shfl(mn, 0);   // raw min of row
#pragma unroll
    for (int c = 0; c < 2; ++c) {
        float s   = seg[((size_t)b * 2 + c) * HW_ + i];
        float cut = s * t4r;                 // == top_k(scaled)[3] by monotonicity (s>=0)
        float mnv = s * mnr;                 // == min(scaled)
        float fill = (mnv > 0.f) ? mnv : 0.f;
        if (lane == 0) atomicMax(&F[b * 2 + c], __float_as_uint(fill));
        unsigned* oc = lacc + (size_t)(b * 2 + c) * HW_;
#pragma unroll
        for (int k = 0; k < 36; ++k) {
            float v = s * x[k];
            if (v >= cut) {                  // kept element
                float e = fmaxf(v - mnv, 0.f) + mnv;   // reference's exact fp sequence
                e = (e > 0.f) ? e : 0.f;     // clamp: F>=0 dominates; keeps uint-max order
                int j = ((k >> 2) * 64 + lane) * 4 + (k & 3);
                atomicMax(oc + j, __float_as_uint(e));
            }
        }
    }
}

// Final: global channels = 96-way partial max; local channels = fmax(lacc, F).
__global__ __launch_bounds__(256) void k_final(float* __restrict__ out,
                                               const float* __restrict__ P,
                                               const unsigned* __restrict__ lacc,
                                               const unsigned* __restrict__ F) {
    int idx = blockIdx.x * 256 + threadIdx.x;
    if (idx >= NOUT) return;
    int b = idx / (4 * HW_);
    int c = (idx / HW_) & 3;
    int j = idx % HW_;
    if (c < 2) {
        float m = -__builtin_inff();
        const float* p = P + (((size_t)b * 2 + c) * NP) * HW_ + j;
#pragma unroll 8
        for (int np = 0; np < NP; ++np) m = fmaxf(m, p[(size_t)np * HW_]);
        out[idx] = m;
    } else {
        float f = __uint_as_float(F[b * 2 + (c - 2)]);
        out[idx] = fmaxf(__uint_as_float(lacc[(size_t)(b * 2 + (c - 2)) * HW_ + j]), f);
    }
}

extern "C" void kernel_launch(void* const* d_in, const int* in_sizes, int n_in,
                              void* d_out, int out_size, void* d_ws, size_t ws_size,
                              hipStream_t stream) {
    const float* init_sim = (const float*)d_in[0];
    const float* prev_sim = (const float*)d_in[1];
    const float* init_seg = (const float*)d_in[2];
    const float* prev_seg = (const float*)d_in[3];
    unsigned* ws = (unsigned*)d_ws;
    float* P = (float*)(ws + P_OFF);

    k_init  <<<(P_OFF + 255) / 256, 256, 0, stream>>>(ws);
    k_global<<<dim3(3, NP, B_), 192, 0, stream>>>(init_sim, init_seg, P);
    k_local <<<(B_ * HW_) / 4, 256, 0, stream>>>(prev_sim, prev_seg,
                                                 ws + LACC_OFF, ws + F_OFF);
    k_final <<<(NOUT + 255) / 256, 256, 0, stream>>>((float*)d_out, P,
                                                     ws + LACC_OFF, ws + F_OFF);
}

// Round 3
// 386.218 us; speedup vs baseline: 1.9532x; 1.9532x over previous
//
#include <hip/hip_runtime.h>

// Matcher: B=8, H=W=48, HW=2304.  Zero-atomic design.
// out[b,0..1,:]: global branch  max_p init_sim[b,p,j]*init_seg[b,c,p]
// out[b,2..3,:]: local branch   per-row top4/min on scaled prev_sim rows,
//                column max of (kept value | per-row fill).
#define B_   8
#define HW_  2304
#define NP   48              // p-chunks for partial-max arrays
#define RP   (HW_ / NP)      // 48 rows per chunk
#define NOUT (B_ * 4 * HW_)

// ws layout (float units)
#define ROWS_OFF 0                               // float2 per row: (t4raw, mnraw) x 18432
#define PG_OFF   (B_ * HW_ * 2)                  // global partials: B*2*NP*HW floats
#define PL_OFF   (PG_OFF + B_ * 2 * NP * HW_)    // local  partials: B*2*NP*HW floats

// Pass 1: one wave per row; top4+min of the RAW row; plain store, no atomics.
__global__ __launch_bounds__(256, 4) void k_rows(const float* __restrict__ sim,
                                                 float2* __restrict__ rows) {
    const int r    = blockIdx.x * 4 + (threadIdx.x >> 6);   // row 0..18431
    const int lane = threadIdx.x & 63;
    const float4* row = (const float4*)(sim + (size_t)r * HW_);
    float x[36];
#pragma unroll
    for (int k = 0; k < 9; ++k) {
        float4 v = row[lane + k * 64];
        x[4 * k + 0] = v.x; x[4 * k + 1] = v.y;
        x[4 * k + 2] = v.z; x[4 * k + 3] = v.w;
    }
    const float NI = -__builtin_inff();
    float a0 = NI, a1 = NI, a2 = NI, a3 = NI, mn = __builtin_inff();
#pragma unroll
    for (int k = 0; k < 36; ++k) {
        float v = x[k];
        mn = fminf(mn, v);
        float w = fmaxf(a3, v);                 // branchless sorted-desc top4 insert
        a3 = fminf(a2, w); w = fmaxf(a2, w);
        a2 = fminf(a1, w); w = fmaxf(a1, w);
        a1 = fminf(a0, w); a0 = fmaxf(a0, w);
    }
#pragma unroll
    for (int off = 32; off >= 1; off >>= 1) {   // wave64 merge of sorted 4-lists
        float b0 = __shfl_down(a0, off);
        float b1 = __shfl_down(a1, off);
        float b2 = __shfl_down(a2, off);
        float b3 = __shfl_down(a3, off);
        float bm = __shfl_down(mn, off);
        mn = fminf(mn, bm);
        float r0 = fmaxf(a0, b0);
        float r1 = fmaxf(fmaxf(a1, b1), fminf(a0, b0));
        float r2 = fmaxf(fmaxf(a2, b2), fmaxf(fminf(a1, b0), fminf(a0, b1)));
        float r3 = fmaxf(fmaxf(a3, b3),
                   fmaxf(fminf(a2, b0), fmaxf(fminf(a1, b1), fminf(a0, b2))));
        a0 = r0; a1 = r1; a2 = r2; a3 = r3;
    }
    if (lane == 0) rows[r] = make_float2(a3, mn);   // (4th-largest raw, min raw)
}

// Global branch partials: grid (3, NP, B), 192 threads; no atomics.
__global__ __launch_bounds__(192) void k_global(const float* __restrict__ sim,
                                                const float* __restrict__ seg,
                                                float* __restrict__ P) {
    const int t  = threadIdx.x;
    const int np = blockIdx.y;
    const int b  = blockIdx.z;
    const int j4 = blockIdx.x * 192 + t;          // float4 column 0..575
    const float4* simb = (const float4*)(sim + (size_t)b * HW_ * HW_) + j4;
    const float* sg = seg + (size_t)b * 2 * HW_;
    const int p0 = np * RP;
    const float NI = -__builtin_inff();
    float4 m0 = {NI, NI, NI, NI}, m1 = {NI, NI, NI, NI};
#pragma unroll 8
    for (int rr = 0; rr < RP; ++rr) {
        int p = p0 + rr;
        float4 v = simb[(size_t)p * (HW_ / 4)];
        float s0 = sg[p];
        float s1 = sg[HW_ + p];
        m0.x = fmaxf(m0.x, v.x * s0); m1.x = fmaxf(m1.x, v.x * s1);
        m0.y = fmaxf(m0.y, v.y * s0); m1.y = fmaxf(m1.y, v.y * s1);
        m0.z = fmaxf(m0.z, v.z * s0); m1.z = fmaxf(m1.z, v.z * s1);
        m0.w = fmaxf(m0.w, v.w * s0); m1.w = fmaxf(m1.w, v.w * s1);
    }
    float4* P4 = (float4*)P;
    P4[(((size_t)b * 2 + 0) * NP + np) * (HW_ / 4) + j4] = m0;
    P4[(((size_t)b * 2 + 1) * NP + np) * (HW_ / 4) + j4] = m1;
}

// Pass 2: local-branch column partials; each element contributes its exact
// reference value (kept -> fmax(v-mnv,0)+mnv, dropped -> fill). No atomics.
__global__ __launch_bounds__(192) void k_lcol(const float* __restrict__ sim,
                                              const float* __restrict__ seg,
                                              const float2* __restrict__ rows,
                                              float* __restrict__ P) {
    const int t  = threadIdx.x;
    const int np = blockIdx.y;
    const int b  = blockIdx.z;
    const int j4 = blockIdx.x * 192 + t;
    const float4* simb = (const float4*)(sim + (size_t)b * HW_ * HW_) + j4;
    const float* sg = seg + (size_t)b * 2 * HW_;
    const float2* rb = rows + (size_t)b * HW_;
    const int p0 = np * RP;
    const float NI = -__builtin_inff();
    float4 m0 = {NI, NI, NI, NI}, m1 = {NI, NI, NI, NI};
#pragma unroll 4
    for (int rr = 0; rr < RP; ++rr) {
        int p = p0 + rr;
        float4 v = simb[(size_t)p * (HW_ / 4)];
        float2 rd = rb[p];                       // (t4raw, mnraw) — wave-uniform
        float s0 = sg[p];
        float s1 = sg[HW_ + p];
        float cut0 = s0 * rd.x, mnv0 = s0 * rd.y, fill0 = fmaxf(mnv0, 0.f);
        float cut1 = s1 * rd.x, mnv1 = s1 * rd.y, fill1 = fmaxf(mnv1, 0.f);
#define CONTRIB(comp)                                                         \
        {                                                                     \
            float v0 = v.comp * s0, v1 = v.comp * s1;                         \
            float e0 = fmaxf(v0 - mnv0, 0.f) + mnv0;                          \
            float e1 = fmaxf(v1 - mnv1, 0.f) + mnv1;                          \
            float c0 = (v0 >= cut0) ? e0 : fill0;                             \
            float c1 = (v1 >= cut1) ? e1 : fill1;                             \
            m0.comp = fmaxf(m0.comp, c0);                                     \
            m1.comp = fmaxf(m1.comp, c1);                                     \
        }
        CONTRIB(x) CONTRIB(y) CONTRIB(z) CONTRIB(w)
#undef CONTRIB
    }
    float4* P4 = (float4*)P;
    P4[(((size_t)b * 2 + 0) * NP + np) * (HW_ / 4) + j4] = m0;
    P4[(((size_t)b * 2 + 1) * NP + np) * (HW_ / 4) + j4] = m1;
}

// Final: 48-way partial-max combine for all four channels.
__global__ __launch_bounds__(256) void k_final(float* __restrict__ out,
                                               const float* __restrict__ Pg,
                                               const float* __restrict__ Pl) {
    int idx = blockIdx.x * 256 + threadIdx.x;
    if (idx >= NOUT) return;
    int b = idx / (4 * HW_);
    int c = (idx / HW_) & 3;
    int j = idx % HW_;
    const float* p = ((c < 2) ? Pg : Pl) + (((size_t)b * 2 + (c & 1)) * NP) * HW_ + j;
    float m = -__builtin_inff();
#pragma unroll 8
    for (int np = 0; np < NP; ++np) m = fmaxf(m, p[(size_t)np * HW_]);
    out[idx] = m;
}

extern "C" void kernel_launch(void* const* d_in, const int* in_sizes, int n_in,
                              void* d_out, int out_size, void* d_ws, size_t ws_size,
                              hipStream_t stream) {
    const float* init_sim = (const float*)d_in[0];
    const float* prev_sim = (const float*)d_in[1];
    const float* init_seg = (const float*)d_in[2];
    const float* prev_seg = (const float*)d_in[3];
    float* ws = (float*)d_ws;
    float2* rows = (float2*)(ws + ROWS_OFF);
    float* Pg = ws + PG_OFF;
    float* Pl = ws + PL_OFF;

    k_rows  <<<(B_ * HW_) / 4, 256, 0, stream>>>(prev_sim, rows);
    k_lcol  <<<dim3(3, NP, B_), 192, 0, stream>>>(prev_sim, prev_seg, rows, Pl);
    k_global<<<dim3(3, NP, B_), 192, 0, stream>>>(init_sim, init_seg, Pg);
    k_final <<<(NOUT + 255) / 256, 256, 0, stream>>>((float*)d_out, Pg, Pl);
}